// Round 12
// baseline (207.600 us; speedup 1.0000x reference)
//
#include <hip/hip_runtime.h>
#include <math.h>

typedef unsigned short u16;
typedef float f32x4 __attribute__((ext_vector_type(4)));
typedef short s16x4 __attribute__((ext_vector_type(4)));
typedef short s16x8 __attribute__((ext_vector_type(8)));

#define AS3 __attribute__((address_space(3)))
#define AS1 __attribute__((address_space(1)))

__device__ __forceinline__ u16 f2bf(float f) {
  unsigned x = __builtin_bit_cast(unsigned, f);
  x += 0x7fffu + ((x >> 16) & 1u);
  return (u16)(x >> 16);
}
__device__ __forceinline__ float bf2f(u16 u) {
  unsigned x = ((unsigned)u) << 16;
  return __builtin_bit_cast(float, x);
}
__device__ __forceinline__ void gload16(const void* g, void* l) {
  __builtin_amdgcn_global_load_lds((const AS1 void*)g, (AS3 void*)l, 16, 0, 0);
}
// fast sigmoid/tanh via v_exp_f32 (2^x) + v_rcp_f32; ~1ulp, far below bf16 rounding
__device__ __forceinline__ float fsig(float x) {
  return __builtin_amdgcn_rcpf(1.0f + __builtin_amdgcn_exp2f(-1.44269504f * x));
}
__device__ __forceinline__ float ftanh(float x) {
  return 1.0f - 2.0f * __builtin_amdgcn_rcpf(1.0f + __builtin_amdgcn_exp2f(2.88539008f * x));
}

// ---------------- adjacency preprocessing ----------------
__global__ void k_dinv(const float* __restrict__ adj, float* __restrict__ dinv) {
  int j = blockIdx.x;
  float s = 0.0f;
  for (int i = threadIdx.x; i < 512; i += 64) s += adj[(size_t)j * 512 + i];
  #pragma unroll
  for (int off = 32; off > 0; off >>= 1) s += __shfl_down(s, off);
  if (threadIdx.x == 0) dinv[j] = 1.0f / (1.0f + s);
}

// Ab[n][m] = (adj[m][n] + (n==m)) * dinv[m]   (random-walk transpose), bf16
__global__ void k_buildA(const float* __restrict__ adj, const float* __restrict__ dinv,
                         u16* __restrict__ Ab) {
  int i = blockIdx.x;
  for (int j = threadIdx.x; j < 512; j += 256) {
    float v = adj[(size_t)j * 512 + i] + ((i == j) ? 1.0f : 0.0f);
    Ab[(size_t)i * 512 + j] = f2bf(v * dinv[j]);
  }
}

// state fp32 -> node-major bf16 (XG0n) AND f-major bf16 (XG0t), one read
__global__ __launch_bounds__(256) void k_prepST(const float* __restrict__ s,
                                                u16* __restrict__ Xn,
                                                u16* __restrict__ Xt) {
  __shared__ float Tl[64][65];
  const int b = blockIdx.y, n0 = blockIdx.x * 64;
  const int tid = threadIdx.x;
  const int r = tid >> 4, c4 = (tid & 15) * 4;
  #pragma unroll
  for (int i = 0; i < 4; ++i) {
    f32x4 v = *(const f32x4*)&s[((size_t)b * 512 + n0 + i * 16 + r) * 64 + c4];
    s16x4 o;
    #pragma unroll
    for (int j = 0; j < 4; ++j) { Tl[c4 + j][i * 16 + r] = v[j]; o[j] = (short)f2bf(v[j]); }
    *(s16x4*)&Xn[((size_t)b * 512 + n0 + i * 16 + r) * 64 + c4] = o;
  }
  __syncthreads();
  #pragma unroll
  for (int i = 0; i < 4; ++i) {
    int d = i * 16 + r;
    s16x4 o;
    #pragma unroll
    for (int j = 0; j < 4; ++j) o[j] = (short)f2bf(Tl[d][c4 + j]);
    *(s16x4*)&Xt[((size_t)b * 64 + d) * 512 + n0 + c4] = o;
  }
}

// inp[b][m*2+c] -> Xi0t[(b*2+c)*512 + m]  (bf16, channel-major rows; Xi0t = XAll0t tail)
__global__ void k_prepI(const float* __restrict__ inp, u16* __restrict__ Xi0t) {
  const int b = blockIdx.x, t = threadIdx.x;
  const int m2 = t * 2;
  f32x4 v = *(const f32x4*)&inp[(size_t)b * 1024 + m2 * 2];
  unsigned p0 = (unsigned)f2bf(v.x) | ((unsigned)f2bf(v.z) << 16);
  unsigned p1 = (unsigned)f2bf(v.y) | ((unsigned)f2bf(v.w) << 16);
  *(unsigned*)&Xi0t[((size_t)b * 2 + 0) * 512 + m2] = p0;
  *(unsigned*)&Xi0t[((size_t)b * 2 + 1) * 512 + m2] = p1;
}

// WTp[col][kt][g][j] (224 u16/col): per-thread MFMA A-fragment, one 16B load.
// Chebyshev WEIGHT FOLDING (r8-proven): k1==0 -> W0-W2; k1==1 -> W1; k1==2 -> 2*W2
template<int NC>
__global__ void k_wtp(const float* __restrict__ W, u16* __restrict__ WTp) {
  int col = blockIdx.x, tid = threadIdx.x;
  if (tid >= 224) return;
  int kt = tid >> 5, g = (tid >> 3) & 3, j = tid & 7;
  int kappa = 32 * kt + 4 * g + ((j < 4) ? j : j + 12);
  float v = 0.0f;
  if (kappa < 192) {
    int f = kappa & 63, k1 = kappa >> 6;
    const float* base = &W[(size_t)((f + 2) * 3) * NC + col];
    v = (k1 == 0) ? base[0] - base[2 * NC]
      : (k1 == 1) ? base[1 * NC]
                  : 2.0f * base[2 * NC];
  } else if (kappa < 198) {
    int t = kappa - 192, k1 = t >> 1, c = t & 1;
    const float* base = &W[(size_t)(c * 3) * NC + col];
    v = (k1 == 0) ? base[0] - base[2 * NC]
      : (k1 == 1) ? base[1 * NC]
                  : 2.0f * base[2 * NC];
  }
  WTp[(size_t)col * 224 + tid] = f2bf(v);
}

// ---------------- diffusion GEMM: Yt[R][n] = sum_m Xt[R][m]*Ab[n][m] ----------------
// Block 64R x 128n, 4 waves (2 Rg x 2 ng), BK=32, double-buffered; ~4 blocks/CU for TLP.
template<int WTB, int WNB>
__global__ __launch_bounds__(256, 4) void k_diffB(const u16* __restrict__ Xt,
                                                  const u16* __restrict__ Ab,
                                                  u16* __restrict__ Yt,
                                                  u16* __restrict__ Yn) {
  __shared__ __align__(16) u16 SB[12288];  // Xl dbuf 2x2048 @0; Ab dbuf 2x4096 @4096
  const int tid = threadIdx.x;
  const int w = tid >> 6, l = tid & 63, g = l >> 4, l16 = l & 15;
  const int Rg = w >> 1, ng = w & 1;
  const int nt0 = blockIdx.x * 128;
  const size_t R0 = (size_t)blockIdx.y * 64;
  const bool isInput = (R0 >= 16384);
  f32x4 acc[2][4] = {};

#define STAGE(BUF, M0)                                                            \
  {                                                                               \
    { int r_ = tid >> 2, p_ = tid & 3;                                            \
      gload16(&Xt[(R0 + r_) * 512 + (M0) + 8 * (p_ ^ (r_ & 3))],                  \
              &SB[(BUF) * 2048 + tid * 8]); }                                     \
    _Pragma("unroll")                                                             \
    for (int i_ = 0; i_ < 2; ++i_) {                                              \
      int s_ = i_ * 256 + tid, r_ = s_ >> 2, p_ = s_ & 3;                         \
      gload16(&Ab[(size_t)(nt0 + r_) * 512 + (M0) + 8 * (p_ ^ (r_ & 3))],         \
              &SB[4096 + (BUF) * 4096 + s_ * 8]);                                 \
    }                                                                             \
  }

  STAGE(0, 0);
  #pragma unroll
  for (int it = 0; it < 16; ++it) {
    const int cur = it & 1;
    if (it < 15) {
      if (cur == 0) STAGE(1, (it + 1) * 32)
      else          STAGE(0, (it + 1) * 32)
      asm volatile("s_waitcnt vmcnt(3)" ::: "memory");
    } else {
      asm volatile("s_waitcnt vmcnt(0)" ::: "memory");
    }
    __builtin_amdgcn_s_barrier();
    __builtin_amdgcn_sched_barrier(0);

    const u16* XL = &SB[cur * 2048];
    const u16* AL = &SB[4096 + cur * 4096];
    s16x8 af[2], bf[4];
    #pragma unroll
    for (int mt = 0; mt < 2; ++mt) {
      int r = Rg * 32 + mt * 16 + l16;
      const char* rowp = (const char*)XL + r * 64 + 8 * (g & 1);
      int c0 = (g >> 1), c1 = c0 + 2;
      s16x4 lo = *(const s16x4*)(rowp + 16 * (c0 ^ (r & 3)));
      s16x4 hi = *(const s16x4*)(rowp + 16 * (c1 ^ (r & 3)));
      af[mt] = __builtin_shufflevector(lo, hi, 0, 1, 2, 3, 4, 5, 6, 7);
    }
    #pragma unroll
    for (int nt = 0; nt < 4; ++nt) {
      int r = ng * 64 + nt * 16 + l16;
      const char* rowp = (const char*)AL + r * 64 + 8 * (g & 1);
      int c0 = (g >> 1), c1 = c0 + 2;
      s16x4 lo = *(const s16x4*)(rowp + 16 * (c0 ^ (r & 3)));
      s16x4 hi = *(const s16x4*)(rowp + 16 * (c1 ^ (r & 3)));
      bf[nt] = __builtin_shufflevector(lo, hi, 0, 1, 2, 3, 4, 5, 6, 7);
    }
    #pragma unroll
    for (int mt = 0; mt < 2; ++mt)
      #pragma unroll
      for (int nt = 0; nt < 4; ++nt)
        acc[mt][nt] = __builtin_amdgcn_mfma_f32_16x16x32_bf16(af[mt], bf[nt],
                                                              acc[mt][nt], 0, 0, 0);
    __builtin_amdgcn_s_barrier();
    __builtin_amdgcn_sched_barrier(0);
  }
#undef STAGE

  if (WNB && !isInput) {
    #pragma unroll
    for (int mt = 0; mt < 2; ++mt)
      #pragma unroll
      for (int nt = 0; nt < 4; ++nt) {
        size_t R = R0 + Rg * 32 + mt * 16 + 4 * g;
        int n = nt0 + ng * 64 + nt * 16 + l16;
        s16x4 o;
        #pragma unroll
        for (int rr = 0; rr < 4; ++rr) o[rr] = (short)f2bf(acc[mt][nt][rr]);
        *(s16x4*)&Yn[((R >> 6) * 512 + n) * 64 + (R & 63)] = o;
      }
  }

  if (WTB || isInput) {
    #pragma unroll
    for (int mt = 0; mt < 2; ++mt)
      #pragma unroll
      for (int nt = 0; nt < 4; ++nt) {
        int nl = ng * 64 + nt * 16 + l16;
        #pragma unroll
        for (int rr = 0; rr < 4; ++rr) {
          int Rl = Rg * 32 + mt * 16 + 4 * g + rr;
          SB[Rl * 128 + nl] = f2bf(acc[mt][nt][rr]);
        }
      }
    __syncthreads();
    #pragma unroll
    for (int i = 0; i < 4; ++i) {
      int s = i * 256 + tid, r = s >> 4, c = s & 15;
      *(s16x8*)&Yt[(R0 + r) * 512 + nt0 + c * 8] = *(const s16x8*)&SB[r * 128 + c * 8];
    }
  }
}

// ---------------- gate applyW, 32-node tiles: NC=128 (r11-proven) ----------------
__global__ __launch_bounds__(256) void k_applyG(
    const u16* __restrict__ S0b, const u16* __restrict__ S1b, const u16* __restrict__ S2b,
    const float* __restrict__ inp, const u16* __restrict__ Yi1, const u16* __restrict__ Yi2,
    const u16* __restrict__ WTp, const float* __restrict__ bias,
    u16* __restrict__ XC0n, u16* __restrict__ XC0t, u16* __restrict__ Ub) {
  __shared__ __align__(16) u16 Sl[3][2048];   // [32 rows][64 f], swizzled chunks
  __shared__ __align__(16) u16 St[32 * 36];   // tail k-tile [32 rows][36]
  const int tid = threadIdx.x;
  const int w = tid >> 6, l = tid & 63, g = l >> 4, l16 = l & 15;
  const int b = blockIdx.y, n0 = blockIdx.x * 32;
  const int colr = w * 16 + l16;

  const u16* Sb[3] = {S0b, S1b, S2b};
  #pragma unroll
  for (int k1 = 0; k1 < 3; ++k1) {
    int r = tid >> 3, p = tid & 7;
    gload16(&Sb[k1][((size_t)b * 512 + n0 + r) * 64 + 8 * (p ^ (r & 7))],
            &Sl[k1][(w * 64) * 8]);
  }
  s16x8 aw[7][2];
  {
    const u16* w0 = WTp + (size_t)colr * 224 + g * 8;
    const u16* w1 = WTp + (size_t)(colr + 64) * 224 + g * 8;
    #pragma unroll
    for (int kt = 0; kt < 7; ++kt) {
      aw[kt][0] = *(const s16x8*)&w0[kt * 32];
      aw[kt][1] = *(const s16x8*)&w1[kt * 32];
    }
  }
  for (int i = tid; i < 32 * 36; i += 256)
    if ((i % 36) >= 6) St[i] = 0;
  if (tid < 192) {
    int k1 = tid >> 6, rr = (tid >> 1) & 31, c = tid & 1;
    u16 v;
    if (k1 == 0) v = f2bf(inp[((size_t)b * 512 + n0 + rr) * 2 + c]);
    else {
      const u16* Yk = (k1 == 1) ? Yi1 : Yi2;
      v = Yk[((size_t)b * 2 + c) * 512 + (n0 + rr)];
    }
    St[rr * 36 + k1 * 2 + c] = v;
  }
  asm volatile("s_waitcnt vmcnt(0)" ::: "memory");
  __syncthreads();

  f32x4 acc0[2] = {}, acc1[2] = {};
  #pragma unroll
  for (int kt = 0; kt < 7; ++kt) {
    #pragma unroll
    for (int ns = 0; ns < 2; ++ns) {
      int rn = ns * 16 + l16;
      s16x4 lo, hi;
      if (kt < 6) {
        const int buf = kt >> 1, ft = kt & 1;
        int c0 = ft * 4 + (g >> 1), c1 = c0 + 2;
        const char* rowp = (const char*)Sl[buf] + rn * 128 + 8 * (g & 1);
        lo = *(const s16x4*)(rowp + 16 * (c0 ^ (rn & 7)));
        hi = *(const s16x4*)(rowp + 16 * (c1 ^ (rn & 7)));
      } else {
        const char* rowp = (const char*)St + rn * 72 + 8 * g;
        lo = *(const s16x4*)(rowp);
        hi = *(const s16x4*)(rowp + 32);
      }
      s16x8 bs = __builtin_shufflevector(lo, hi, 0, 1, 2, 3, 4, 5, 6, 7);
      acc0[ns] = __builtin_amdgcn_mfma_f32_16x16x32_bf16(aw[kt][0], bs, acc0[ns], 0, 0, 0);
      acc1[ns] = __builtin_amdgcn_mfma_f32_16x16x32_bf16(aw[kt][1], bs, acc1[ns], 0, 0, 0);
    }
  }
  __syncthreads();   // all waves done reading Sl[1] before bounce reuse

  f32x4 b4r = *(const f32x4*)&bias[w * 16 + 4 * g];
  f32x4 b4u = *(const f32x4*)&bias[64 + w * 16 + 4 * g];
  const int chk = 2 * w + (g >> 1);
  #pragma unroll
  for (int ns = 0; ns < 2; ++ns) {
    int rn = ns * 16 + l16;
    int n = n0 + rn;
    size_t base = ((size_t)b * 512 + n) * 64 + w * 16 + 4 * g;
    const char* srow = (const char*)Sl[0] + rn * 128 + 8 * (g & 1);
    s16x4 st4 = *(const s16x4*)(srow + 16 * (chk ^ (rn & 7)));
    s16x4 o;
    #pragma unroll
    for (int r = 0; r < 4; ++r) {
      float x = acc0[ns][r] + b4r[r];
      o[r] = (short)f2bf(fsig(x) * bf2f((u16)st4[r]));
    }
    *(s16x4*)&XC0n[base] = o;
    #pragma unroll
    for (int r = 0; r < 4; ++r)
      Sl[1][(w * 16 + 4 * g + r) * 32 + rn] = (u16)o[r];   // bounce tile [64f][32n]
    s16x4 uo;
    #pragma unroll
    for (int r = 0; r < 4; ++r) {
      float x = acc1[ns][r] + b4u[r];
      uo[r] = (short)f2bf(fsig(x));
    }
    *(s16x4*)&Ub[base] = uo;
  }
  __syncthreads();
  {
    int f = tid >> 2, c = tid & 3;
    *(s16x8*)&XC0t[(size_t)(b * 64 + f) * 512 + n0 + c * 8] =
        *(const s16x8*)&Sl[1][f * 32 + c * 8];
  }
}

// ---------------- candidate applyW, 32-node tiles: NC=64 ----------------
__global__ __launch_bounds__(256) void k_applyC(
    const u16* __restrict__ S0b, const u16* __restrict__ S1b, const u16* __restrict__ S2b,
    const float* __restrict__ inp, const u16* __restrict__ Yi1, const u16* __restrict__ Yi2,
    const u16* __restrict__ WTp, const float* __restrict__ bias,
    const float* __restrict__ state, const u16* __restrict__ Ub, float* __restrict__ outp) {
  __shared__ __align__(16) u16 Sl[3][2048];
  __shared__ __align__(16) u16 St[32 * 36];
  const int tid = threadIdx.x;
  const int w = tid >> 6, l = tid & 63, g = l >> 4, l16 = l & 15;
  const int b = blockIdx.y, n0 = blockIdx.x * 32;
  const int colr = w * 16 + l16;

  const u16* Sb[3] = {S0b, S1b, S2b};
  #pragma unroll
  for (int k1 = 0; k1 < 3; ++k1) {
    int r = tid >> 3, p = tid & 7;
    gload16(&Sb[k1][((size_t)b * 512 + n0 + r) * 64 + 8 * (p ^ (r & 7))],
            &Sl[k1][(w * 64) * 8]);
  }
  s16x8 aw[7];
  {
    const u16* w0 = WTp + (size_t)colr * 224 + g * 8;
    #pragma unroll
    for (int kt = 0; kt < 7; ++kt) aw[kt] = *(const s16x8*)&w0[kt * 32];
  }
  for (int i = tid; i < 32 * 36; i += 256)
    if ((i % 36) >= 6) St[i] = 0;
  if (tid < 192) {
    int k1 = tid >> 6, rr = (tid >> 1) & 31, c = tid & 1;
    u16 v;
    if (k1 == 0) v = f2bf(inp[((size_t)b * 512 + n0 + rr) * 2 + c]);
    else {
      const u16* Yk = (k1 == 1) ? Yi1 : Yi2;
      v = Yk[((size_t)b * 2 + c) * 512 + (n0 + rr)];
    }
    St[rr * 36 + k1 * 2 + c] = v;
  }
  asm volatile("s_waitcnt vmcnt(0)" ::: "memory");
  __syncthreads();

  f32x4 acc[2] = {};
  #pragma unroll
  for (int kt = 0; kt < 7; ++kt) {
    #pragma unroll
    for (int ns = 0; ns < 2; ++ns) {
      int rn = ns * 16 + l16;
      s16x4 lo, hi;
      if (kt < 6) {
        const int buf = kt >> 1, ft = kt & 1;
        int c0 = ft * 4 + (g >> 1), c1 = c0 + 2;
        const char* rowp = (const char*)Sl[buf] + rn * 128 + 8 * (g & 1);
        lo = *(const s16x4*)(rowp + 16 * (c0 ^ (rn & 7)));
        hi = *(const s16x4*)(rowp + 16 * (c1 ^ (rn & 7)));
      } else {
        const char* rowp = (const char*)St + rn * 72 + 8 * g;
        lo = *(const s16x4*)(rowp);
        hi = *(const s16x4*)(rowp + 32);
      }
      s16x8 bs = __builtin_shufflevector(lo, hi, 0, 1, 2, 3, 4, 5, 6, 7);
      acc[ns] = __builtin_amdgcn_mfma_f32_16x16x32_bf16(aw[kt], bs, acc[ns], 0, 0, 0);
    }
  }

  f32x4 b4 = *(const f32x4*)&bias[w * 16 + 4 * g];
  #pragma unroll
  for (int ns = 0; ns < 2; ++ns) {
    int n = n0 + ns * 16 + l16;
    size_t base = ((size_t)b * 512 + n) * 64 + w * 16 + 4 * g;
    s16x4 ub4 = *(const s16x4*)&Ub[base];
    f32x4 st4 = *(const f32x4*)&state[base];
    f32x4 o;
    #pragma unroll
    for (int r = 0; r < 4; ++r) {
      float c = ftanh(acc[ns][r] + b4[r]);
      float u = bf2f((u16)ub4[r]);
      o[r] = fmaf(u, st4[r] - c, c);
    }
    *(f32x4*)&outp[base] = o;
  }
}

extern "C" void kernel_launch(void* const* d_in, const int* in_sizes, int n_in,
                              void* d_out, int out_size, void* d_ws, size_t ws_size,
                              hipStream_t stream) {
  const float* inp   = (const float*)d_in[0];
  const float* state = (const float*)d_in[1];
  const float* adj   = (const float*)d_in[2];
  const float* Wg    = (const float*)d_in[3];
  const float* bg    = (const float*)d_in[4];
  const float* Wc    = (const float*)d_in[5];
  const float* bc    = (const float*)d_in[6];
  float* out = (float*)d_out;

  char* p = (char*)d_ws;
  u16* Abf    = (u16*)p; p += 524288;      // Ab[n][m]
  u16* XAll0t = (u16*)p; p += 17301504;    // [16896][512]: XG0t (later XC0t) + Xi0t tail
  u16* X1t    = (u16*)p; p += 17301504;    // [16896][512]: X1t batch + Yi1t tail
  u16* Yi2t   = (u16*)p; p += 524288;      // [512][512] (plain A@Yi1; weights folded)
  u16* WTpg   = (u16*)p; p += 57344;       // [128][224] permuted + folded
  u16* WTpc   = (u16*)p; p += 28672;       // [64][224]
  float* dinv = (float*)p; p += 2048;
  u16* XG0n   = (u16*)p; p += 16777216;    // [b][n][64]; reused as Ub after applyG stages it
  u16* XC0n   = (u16*)p; p += 16777216;
  u16* X1n    = (u16*)p; p += 16777216;
  u16* X2n    = (u16*)p; p += 16777216;    // total ~98.1 MB
  u16* Xi0t   = XAll0t + (size_t)16384 * 512;
  u16* XC0t   = XAll0t;                    // alias: XG0t dead after gate hop1
  u16* Yi1t   = X1t + (size_t)16384 * 512;
  u16* Yi2off = Yi2t - (size_t)16384 * 512;  // Yt base for hop2 (only R>=16384 deref'd)
  u16* Ub     = XG0n;                      // alias: same-block footprint, staged before written

  k_dinv   <<<512, 64,  0, stream>>>(adj, dinv);
  k_buildA <<<512, 256, 0, stream>>>(adj, dinv, Abf);
  k_prepST <<<dim3(8, 256), 256, 0, stream>>>(state, XG0n, XAll0t);
  k_prepI  <<<256, 256, 0, stream>>>(inp, Xi0t);
  k_wtp<128><<<128, 256, 0, stream>>>(Wg, WTpg);
  k_wtp<64> <<<64, 256, 0, stream>>>(Wc, WTpc);

  // gate hop1 (batch + input rows) -> X1t (+Yi1t tail), X1n
  k_diffB<1, 1><<<dim3(4, 264), 256, 0, stream>>>(XAll0t, Abf, X1t, X1n);
  // gate hop2 (plain A@X1, folded): batch -> X2n; input rows -> Yi2t
  k_diffB<0, 1><<<dim3(4, 264), 256, 0, stream>>>(X1t, Abf, Yi2off, X2n);
  k_applyG<<<dim3(16, 256), 256, 0, stream>>>(XG0n, X1n, X2n, inp, Yi1t, Yi2t,
                                              WTpg, bg, XC0n, XC0t, Ub);

  // candidate path (batch rows only; input diffusion reused)
  k_diffB<1, 1><<<dim3(4, 256), 256, 0, stream>>>(XC0t, Abf, X1t, X1n);
  k_diffB<0, 1><<<dim3(4, 256), 256, 0, stream>>>(X1t, Abf, Yi2off, X2n);
  k_applyC<<<dim3(16, 256), 256, 0, stream>>>(XC0n, X1n, X2n, inp, Yi1t, Yi2t,
                                              WTpc, bc, state, Ub, out);
}

// Round 13
// 192.350 us; speedup vs baseline: 1.0793x; 1.0793x over previous
//
#include <hip/hip_runtime.h>
#include <math.h>

typedef unsigned short u16;
typedef float f32x4 __attribute__((ext_vector_type(4)));
typedef short s16x4 __attribute__((ext_vector_type(4)));
typedef short s16x8 __attribute__((ext_vector_type(8)));

#define AS3 __attribute__((address_space(3)))
#define AS1 __attribute__((address_space(1)))

__device__ __forceinline__ u16 f2bf(float f) {
  unsigned x = __builtin_bit_cast(unsigned, f);
  x += 0x7fffu + ((x >> 16) & 1u);
  return (u16)(x >> 16);
}
__device__ __forceinline__ float bf2f(u16 u) {
  unsigned x = ((unsigned)u) << 16;
  return __builtin_bit_cast(float, x);
}
__device__ __forceinline__ void gload16(const void* g, void* l) {
  __builtin_amdgcn_global_load_lds((const AS1 void*)g, (AS3 void*)l, 16, 0, 0);
}
// fast sigmoid/tanh via v_exp_f32 (2^x) + v_rcp_f32; ~1ulp, far below bf16 rounding
__device__ __forceinline__ float fsig(float x) {
  return __builtin_amdgcn_rcpf(1.0f + __builtin_amdgcn_exp2f(-1.44269504f * x));
}
__device__ __forceinline__ float ftanh(float x) {
  return 1.0f - 2.0f * __builtin_amdgcn_rcpf(1.0f + __builtin_amdgcn_exp2f(2.88539008f * x));
}

// ---------------- adjacency preprocessing ----------------
__global__ void k_dinv(const float* __restrict__ adj, float* __restrict__ dinv) {
  int j = blockIdx.x;
  float s = 0.0f;
  for (int i = threadIdx.x; i < 512; i += 64) s += adj[(size_t)j * 512 + i];
  #pragma unroll
  for (int off = 32; off > 0; off >>= 1) s += __shfl_down(s, off);
  if (threadIdx.x == 0) dinv[j] = 1.0f / (1.0f + s);
}

// Ab[n][m] = (adj[m][n] + (n==m)) * dinv[m]   (random-walk transpose), bf16
__global__ void k_buildA(const float* __restrict__ adj, const float* __restrict__ dinv,
                         u16* __restrict__ Ab) {
  int i = blockIdx.x;
  for (int j = threadIdx.x; j < 512; j += 256) {
    float v = adj[(size_t)j * 512 + i] + ((i == j) ? 1.0f : 0.0f);
    Ab[(size_t)i * 512 + j] = f2bf(v * dinv[j]);
  }
}

// state fp32 -> node-major bf16 (XG0n) AND f-major bf16 (XG0t), one read
__global__ __launch_bounds__(256) void k_prepST(const float* __restrict__ s,
                                                u16* __restrict__ Xn,
                                                u16* __restrict__ Xt) {
  __shared__ float Tl[64][65];
  const int b = blockIdx.y, n0 = blockIdx.x * 64;
  const int tid = threadIdx.x;
  const int r = tid >> 4, c4 = (tid & 15) * 4;
  #pragma unroll
  for (int i = 0; i < 4; ++i) {
    f32x4 v = *(const f32x4*)&s[((size_t)b * 512 + n0 + i * 16 + r) * 64 + c4];
    s16x4 o;
    #pragma unroll
    for (int j = 0; j < 4; ++j) { Tl[c4 + j][i * 16 + r] = v[j]; o[j] = (short)f2bf(v[j]); }
    *(s16x4*)&Xn[((size_t)b * 512 + n0 + i * 16 + r) * 64 + c4] = o;
  }
  __syncthreads();
  #pragma unroll
  for (int i = 0; i < 4; ++i) {
    int d = i * 16 + r;
    s16x4 o;
    #pragma unroll
    for (int j = 0; j < 4; ++j) o[j] = (short)f2bf(Tl[d][c4 + j]);
    *(s16x4*)&Xt[((size_t)b * 64 + d) * 512 + n0 + c4] = o;
  }
}

// inp[b][m*2+c] -> Xi0t[(b*2+c)*512 + m]  (bf16, channel-major rows; Xi0t = XAll0t tail)
__global__ void k_prepI(const float* __restrict__ inp, u16* __restrict__ Xi0t) {
  const int b = blockIdx.x, t = threadIdx.x;
  const int m2 = t * 2;
  f32x4 v = *(const f32x4*)&inp[(size_t)b * 1024 + m2 * 2];
  unsigned p0 = (unsigned)f2bf(v.x) | ((unsigned)f2bf(v.z) << 16);
  unsigned p1 = (unsigned)f2bf(v.y) | ((unsigned)f2bf(v.w) << 16);
  *(unsigned*)&Xi0t[((size_t)b * 2 + 0) * 512 + m2] = p0;
  *(unsigned*)&Xi0t[((size_t)b * 2 + 1) * 512 + m2] = p1;
}

// WTp[col][kt][g][j] (224 u16/col): per-thread MFMA A-fragment, one 16B load.
// Chebyshev WEIGHT FOLDING (r8-proven): k1==0 -> W0-W2; k1==1 -> W1; k1==2 -> 2*W2
template<int NC>
__global__ void k_wtp(const float* __restrict__ W, u16* __restrict__ WTp) {
  int col = blockIdx.x, tid = threadIdx.x;
  if (tid >= 224) return;
  int kt = tid >> 5, g = (tid >> 3) & 3, j = tid & 7;
  int kappa = 32 * kt + 4 * g + ((j < 4) ? j : j + 12);
  float v = 0.0f;
  if (kappa < 192) {
    int f = kappa & 63, k1 = kappa >> 6;
    const float* base = &W[(size_t)((f + 2) * 3) * NC + col];
    v = (k1 == 0) ? base[0] - base[2 * NC]
      : (k1 == 1) ? base[1 * NC]
                  : 2.0f * base[2 * NC];
  } else if (kappa < 198) {
    int t = kappa - 192, k1 = t >> 1, c = t & 1;
    const float* base = &W[(size_t)(c * 3) * NC + col];
    v = (k1 == 0) ? base[0] - base[2 * NC]
      : (k1 == 1) ? base[1 * NC]
                  : 2.0f * base[2 * NC];
  }
  WTp[(size_t)col * 224 + tid] = f2bf(v);
}

// ---------------- diffusion GEMM: Yt[R][n] = sum_m Xt[R][m]*Ab[n][m] (r11-proven) ----
template<int WTB, int WNB>
__global__ __launch_bounds__(256, 3) void k_diffB(const u16* __restrict__ Xt,
                                                  const u16* __restrict__ Ab,
                                                  u16* __restrict__ Yt,
                                                  u16* __restrict__ Yn) {
  __shared__ __align__(16) u16 SB[16384];
  const int tid = threadIdx.x;
  const int w = tid >> 6, l = tid & 63, g = l >> 4, l16 = l & 15;
  const int Rg = w >> 1, ng = w & 1;
  const int nt0 = blockIdx.x * 128;
  const size_t R0 = (size_t)blockIdx.y * 128;
  const bool isInput = (R0 >= 16384);
  f32x4 acc[4][4] = {};

#define STAGE(BUF, M0)                                                            \
  {                                                                               \
    _Pragma("unroll")                                                             \
    for (int i_ = 0; i_ < 2; ++i_) {                                              \
      int s_ = i_ * 256 + tid, r_ = s_ >> 2, p_ = s_ & 3;                         \
      gload16(&Xt[(R0 + r_) * 512 + (M0) + 8 * (p_ ^ (r_ & 3))],                  \
              &SB[(BUF) * 4096 + s_ * 8]);                                        \
      gload16(&Ab[(size_t)(nt0 + r_) * 512 + (M0) + 8 * (p_ ^ (r_ & 3))],         \
              &SB[8192 + (BUF) * 4096 + s_ * 8]);                                 \
    }                                                                             \
  }

  STAGE(0, 0);
  #pragma unroll
  for (int it = 0; it < 16; ++it) {
    const int cur = it & 1;
    if (it < 15) {
      if (cur == 0) STAGE(1, (it + 1) * 32)
      else          STAGE(0, (it + 1) * 32)
      asm volatile("s_waitcnt vmcnt(4)" ::: "memory");
    } else {
      asm volatile("s_waitcnt vmcnt(0)" ::: "memory");
    }
    __builtin_amdgcn_s_barrier();
    __builtin_amdgcn_sched_barrier(0);

    const u16* XL = &SB[cur * 4096];
    const u16* AL = &SB[8192 + cur * 4096];
    s16x8 af[4], bf[4];
    #pragma unroll
    for (int mt = 0; mt < 4; ++mt) {
      int r = Rg * 64 + mt * 16 + l16;
      const char* rowp = (const char*)XL + r * 64 + 8 * (g & 1);
      int c0 = (g >> 1), c1 = c0 + 2;
      s16x4 lo = *(const s16x4*)(rowp + 16 * (c0 ^ (r & 3)));
      s16x4 hi = *(const s16x4*)(rowp + 16 * (c1 ^ (r & 3)));
      af[mt] = __builtin_shufflevector(lo, hi, 0, 1, 2, 3, 4, 5, 6, 7);
    }
    #pragma unroll
    for (int nt = 0; nt < 4; ++nt) {
      int r = ng * 64 + nt * 16 + l16;
      const char* rowp = (const char*)AL + r * 64 + 8 * (g & 1);
      int c0 = (g >> 1), c1 = c0 + 2;
      s16x4 lo = *(const s16x4*)(rowp + 16 * (c0 ^ (r & 3)));
      s16x4 hi = *(const s16x4*)(rowp + 16 * (c1 ^ (r & 3)));
      bf[nt] = __builtin_shufflevector(lo, hi, 0, 1, 2, 3, 4, 5, 6, 7);
    }
    #pragma unroll
    for (int mt = 0; mt < 4; ++mt)
      #pragma unroll
      for (int nt = 0; nt < 4; ++nt)
        acc[mt][nt] = __builtin_amdgcn_mfma_f32_16x16x32_bf16(af[mt], bf[nt],
                                                              acc[mt][nt], 0, 0, 0);
    __builtin_amdgcn_s_barrier();
    __builtin_amdgcn_sched_barrier(0);
  }
#undef STAGE

  if (WNB && !isInput) {
    #pragma unroll
    for (int mt = 0; mt < 4; ++mt)
      #pragma unroll
      for (int nt = 0; nt < 4; ++nt) {
        size_t R = R0 + Rg * 64 + mt * 16 + 4 * g;
        int n = nt0 + ng * 64 + nt * 16 + l16;
        s16x4 o;
        #pragma unroll
        for (int rr = 0; rr < 4; ++rr) o[rr] = (short)f2bf(acc[mt][nt][rr]);
        *(s16x4*)&Yn[((R >> 6) * 512 + n) * 64 + (R & 63)] = o;
      }
  }

  if (WTB || isInput) {
    #pragma unroll
    for (int mt = 0; mt < 4; ++mt)
      #pragma unroll
      for (int nt = 0; nt < 4; ++nt) {
        int nl = ng * 64 + nt * 16 + l16;
        #pragma unroll
        for (int rr = 0; rr < 4; ++rr) {
          int Rl = Rg * 64 + mt * 16 + 4 * g + rr;
          SB[Rl * 128 + nl] = f2bf(acc[mt][nt][rr]);
        }
      }
    __syncthreads();
    #pragma unroll
    for (int i = 0; i < 8; ++i) {
      int s = i * 256 + tid, r = s >> 4, c = s & 15;
      *(s16x8*)&Yt[(R0 + r) * 512 + nt0 + c * 8] = *(const s16x8*)&SB[r * 128 + c * 8];
    }
  }
}

// ---------------- gate applyW, 32-node tiles: NC=128 (r11-proven + fsig) ----------------
__global__ __launch_bounds__(256) void k_applyG(
    const u16* __restrict__ S0b, const u16* __restrict__ S1b, const u16* __restrict__ S2b,
    const float* __restrict__ inp, const u16* __restrict__ Yi1, const u16* __restrict__ Yi2,
    const u16* __restrict__ WTp, const float* __restrict__ bias,
    u16* __restrict__ XC0n, u16* __restrict__ XC0t, u16* __restrict__ Ub) {
  __shared__ __align__(16) u16 Sl[3][2048];   // [32 rows][64 f], swizzled chunks
  __shared__ __align__(16) u16 St[32 * 36];   // tail k-tile [32 rows][36]
  const int tid = threadIdx.x;
  const int w = tid >> 6, l = tid & 63, g = l >> 4, l16 = l & 15;
  const int b = blockIdx.y, n0 = blockIdx.x * 32;
  const int colr = w * 16 + l16;

  const u16* Sb[3] = {S0b, S1b, S2b};
  #pragma unroll
  for (int k1 = 0; k1 < 3; ++k1) {
    int r = tid >> 3, p = tid & 7;
    gload16(&Sb[k1][((size_t)b * 512 + n0 + r) * 64 + 8 * (p ^ (r & 7))],
            &Sl[k1][(w * 64) * 8]);
  }
  s16x8 aw[7][2];
  {
    const u16* w0 = WTp + (size_t)colr * 224 + g * 8;
    const u16* w1 = WTp + (size_t)(colr + 64) * 224 + g * 8;
    #pragma unroll
    for (int kt = 0; kt < 7; ++kt) {
      aw[kt][0] = *(const s16x8*)&w0[kt * 32];
      aw[kt][1] = *(const s16x8*)&w1[kt * 32];
    }
  }
  for (int i = tid; i < 32 * 36; i += 256)
    if ((i % 36) >= 6) St[i] = 0;
  if (tid < 192) {
    int k1 = tid >> 6, rr = (tid >> 1) & 31, c = tid & 1;
    u16 v;
    if (k1 == 0) v = f2bf(inp[((size_t)b * 512 + n0 + rr) * 2 + c]);
    else {
      const u16* Yk = (k1 == 1) ? Yi1 : Yi2;
      v = Yk[((size_t)b * 2 + c) * 512 + (n0 + rr)];
    }
    St[rr * 36 + k1 * 2 + c] = v;
  }
  asm volatile("s_waitcnt vmcnt(0)" ::: "memory");
  __syncthreads();

  f32x4 acc0[2] = {}, acc1[2] = {};
  #pragma unroll
  for (int kt = 0; kt < 7; ++kt) {
    #pragma unroll
    for (int ns = 0; ns < 2; ++ns) {
      int rn = ns * 16 + l16;
      s16x4 lo, hi;
      if (kt < 6) {
        const int buf = kt >> 1, ft = kt & 1;
        int c0 = ft * 4 + (g >> 1), c1 = c0 + 2;
        const char* rowp = (const char*)Sl[buf] + rn * 128 + 8 * (g & 1);
        lo = *(const s16x4*)(rowp + 16 * (c0 ^ (rn & 7)));
        hi = *(const s16x4*)(rowp + 16 * (c1 ^ (rn & 7)));
      } else {
        const char* rowp = (const char*)St + rn * 72 + 8 * g;
        lo = *(const s16x4*)(rowp);
        hi = *(const s16x4*)(rowp + 32);
      }
      s16x8 bs = __builtin_shufflevector(lo, hi, 0, 1, 2, 3, 4, 5, 6, 7);
      acc0[ns] = __builtin_amdgcn_mfma_f32_16x16x32_bf16(aw[kt][0], bs, acc0[ns], 0, 0, 0);
      acc1[ns] = __builtin_amdgcn_mfma_f32_16x16x32_bf16(aw[kt][1], bs, acc1[ns], 0, 0, 0);
    }
  }
  __syncthreads();   // all waves done reading Sl[1] before bounce reuse

  f32x4 b4r = *(const f32x4*)&bias[w * 16 + 4 * g];
  f32x4 b4u = *(const f32x4*)&bias[64 + w * 16 + 4 * g];
  const int chk = 2 * w + (g >> 1);
  #pragma unroll
  for (int ns = 0; ns < 2; ++ns) {
    int rn = ns * 16 + l16;
    int n = n0 + rn;
    size_t base = ((size_t)b * 512 + n) * 64 + w * 16 + 4 * g;
    const char* srow = (const char*)Sl[0] + rn * 128 + 8 * (g & 1);
    s16x4 st4 = *(const s16x4*)(srow + 16 * (chk ^ (rn & 7)));
    s16x4 o;
    #pragma unroll
    for (int r = 0; r < 4; ++r) {
      float x = acc0[ns][r] + b4r[r];
      o[r] = (short)f2bf(fsig(x) * bf2f((u16)st4[r]));
    }
    *(s16x4*)&XC0n[base] = o;
    #pragma unroll
    for (int r = 0; r < 4; ++r)
      Sl[1][(w * 16 + 4 * g + r) * 32 + rn] = (u16)o[r];   // bounce tile [64f][32n]
    s16x4 uo;
    #pragma unroll
    for (int r = 0; r < 4; ++r) {
      float x = acc1[ns][r] + b4u[r];
      uo[r] = (short)f2bf(fsig(x));
    }
    *(s16x4*)&Ub[base] = uo;
  }
  __syncthreads();
  {
    int f = tid >> 2, c = tid & 3;
    *(s16x8*)&XC0t[(size_t)(b * 64 + f) * 512 + n0 + c * 8] =
        *(const s16x8*)&Sl[1][f * 32 + c * 8];
  }
}

// ---------------- candidate applyW, 32-node tiles: NC=64 (r11-proven + ftanh) ----------
__global__ __launch_bounds__(256) void k_applyC(
    const u16* __restrict__ S0b, const u16* __restrict__ S1b, const u16* __restrict__ S2b,
    const float* __restrict__ inp, const u16* __restrict__ Yi1, const u16* __restrict__ Yi2,
    const u16* __restrict__ WTp, const float* __restrict__ bias,
    const float* __restrict__ state, const u16* __restrict__ Ub, float* __restrict__ outp) {
  __shared__ __align__(16) u16 Sl[3][2048];
  __shared__ __align__(16) u16 St[32 * 36];
  const int tid = threadIdx.x;
  const int w = tid >> 6, l = tid & 63, g = l >> 4, l16 = l & 15;
  const int b = blockIdx.y, n0 = blockIdx.x * 32;
  const int colr = w * 16 + l16;

  const u16* Sb[3] = {S0b, S1b, S2b};
  #pragma unroll
  for (int k1 = 0; k1 < 3; ++k1) {
    int r = tid >> 3, p = tid & 7;
    gload16(&Sb[k1][((size_t)b * 512 + n0 + r) * 64 + 8 * (p ^ (r & 7))],
            &Sl[k1][(w * 64) * 8]);
  }
  s16x8 aw[7];
  {
    const u16* w0 = WTp + (size_t)colr * 224 + g * 8;
    #pragma unroll
    for (int kt = 0; kt < 7; ++kt) aw[kt] = *(const s16x8*)&w0[kt * 32];
  }
  for (int i = tid; i < 32 * 36; i += 256)
    if ((i % 36) >= 6) St[i] = 0;
  if (tid < 192) {
    int k1 = tid >> 6, rr = (tid >> 1) & 31, c = tid & 1;
    u16 v;
    if (k1 == 0) v = f2bf(inp[((size_t)b * 512 + n0 + rr) * 2 + c]);
    else {
      const u16* Yk = (k1 == 1) ? Yi1 : Yi2;
      v = Yk[((size_t)b * 2 + c) * 512 + (n0 + rr)];
    }
    St[rr * 36 + k1 * 2 + c] = v;
  }
  asm volatile("s_waitcnt vmcnt(0)" ::: "memory");
  __syncthreads();

  f32x4 acc[2] = {};
  #pragma unroll
  for (int kt = 0; kt < 7; ++kt) {
    #pragma unroll
    for (int ns = 0; ns < 2; ++ns) {
      int rn = ns * 16 + l16;
      s16x4 lo, hi;
      if (kt < 6) {
        const int buf = kt >> 1, ft = kt & 1;
        int c0 = ft * 4 + (g >> 1), c1 = c0 + 2;
        const char* rowp = (const char*)Sl[buf] + rn * 128 + 8 * (g & 1);
        lo = *(const s16x4*)(rowp + 16 * (c0 ^ (rn & 7)));
        hi = *(const s16x4*)(rowp + 16 * (c1 ^ (rn & 7)));
      } else {
        const char* rowp = (const char*)St + rn * 72 + 8 * g;
        lo = *(const s16x4*)(rowp);
        hi = *(const s16x4*)(rowp + 32);
      }
      s16x8 bs = __builtin_shufflevector(lo, hi, 0, 1, 2, 3, 4, 5, 6, 7);
      acc[ns] = __builtin_amdgcn_mfma_f32_16x16x32_bf16(aw[kt], bs, acc[ns], 0, 0, 0);
    }
  }

  f32x4 b4 = *(const f32x4*)&bias[w * 16 + 4 * g];
  #pragma unroll
  for (int ns = 0; ns < 2; ++ns) {
    int n = n0 + ns * 16 + l16;
    size_t base = ((size_t)b * 512 + n) * 64 + w * 16 + 4 * g;
    s16x4 ub4 = *(const s16x4*)&Ub[base];
    f32x4 st4 = *(const f32x4*)&state[base];
    f32x4 o;
    #pragma unroll
    for (int r = 0; r < 4; ++r) {
      float c = ftanh(acc[ns][r] + b4[r]);
      float u = bf2f((u16)ub4[r]);
      o[r] = fmaf(u, st4[r] - c, c);
    }
    *(f32x4*)&outp[base] = o;
  }
}

extern "C" void kernel_launch(void* const* d_in, const int* in_sizes, int n_in,
                              void* d_out, int out_size, void* d_ws, size_t ws_size,
                              hipStream_t stream) {
  const float* inp   = (const float*)d_in[0];
  const float* state = (const float*)d_in[1];
  const float* adj   = (const float*)d_in[2];
  const float* Wg    = (const float*)d_in[3];
  const float* bg    = (const float*)d_in[4];
  const float* Wc    = (const float*)d_in[5];
  const float* bc    = (const float*)d_in[6];
  float* out = (float*)d_out;

  char* p = (char*)d_ws;
  u16* Abf    = (u16*)p; p += 524288;      // Ab[n][m]
  u16* XAll0t = (u16*)p; p += 17301504;    // [16896][512]: XG0t (later XC0t) + Xi0t tail
  u16* X1t    = (u16*)p; p += 17301504;    // [16896][512]: X1t batch + Yi1t tail
  u16* Yi2t   = (u16*)p; p += 524288;      // [512][512] (plain A@Yi1; weights folded)
  u16* WTpg   = (u16*)p; p += 57344;       // [128][224] permuted + folded
  u16* WTpc   = (u16*)p; p += 28672;       // [64][224]
  float* dinv = (float*)p; p += 2048;
  u16* XG0n   = (u16*)p; p += 16777216;    // [b][n][64]; reused as Ub after applyG stages it
  u16* XC0n   = (u16*)p; p += 16777216;
  u16* X1n    = (u16*)p; p += 16777216;
  u16* X2n    = (u16*)p; p += 16777216;    // total ~98.1 MB
  u16* Xi0t   = XAll0t + (size_t)16384 * 512;
  u16* XC0t   = XAll0t;                    // alias: XG0t dead after gate hop1
  u16* Yi1t   = X1t + (size_t)16384 * 512;
  u16* Yi2off = Yi2t - (size_t)16384 * 512;  // Yt base for hop2 (only R>=16384 deref'd)
  u16* Ub     = XG0n;                      // alias: same-block footprint, staged before written

  k_dinv   <<<512, 64,  0, stream>>>(adj, dinv);
  k_buildA <<<512, 256, 0, stream>>>(adj, dinv, Abf);
  k_prepST <<<dim3(8, 256), 256, 0, stream>>>(state, XG0n, XAll0t);
  k_prepI  <<<256, 256, 0, stream>>>(inp, Xi0t);
  k_wtp<128><<<128, 256, 0, stream>>>(Wg, WTpg);
  k_wtp<64> <<<64, 256, 0, stream>>>(Wc, WTpc);

  // gate hop1 (batch + input rows) -> X1t (+Yi1t tail), X1n
  k_diffB<1, 1><<<dim3(4, 132), 256, 0, stream>>>(XAll0t, Abf, X1t, X1n);
  // gate hop2 (plain A@X1, folded): batch -> X2n; input rows -> Yi2t
  k_diffB<0, 1><<<dim3(4, 132), 256, 0, stream>>>(X1t, Abf, Yi2off, X2n);
  k_applyG<<<dim3(16, 256), 256, 0, stream>>>(XG0n, X1n, X2n, inp, Yi1t, Yi2t,
                                              WTpg, bg, XC0n, XC0t, Ub);

  // candidate path (batch rows only; input diffusion reused)
  k_diffB<1, 1><<<dim3(4, 128), 256, 0, stream>>>(XC0t, Abf, X1t, X1n);
  k_diffB<0, 1><<<dim3(4, 128), 256, 0, stream>>>(X1t, Abf, Yi2off, X2n);
  k_applyC<<<dim3(16, 256), 256, 0, stream>>>(XC0n, X1n, X2n, inp, Yi1t, Yi2t,
                                              WTpc, bc, state, Ub, out);
}

// Round 14
// 188.992 us; speedup vs baseline: 1.0985x; 1.0178x over previous
//
#include <hip/hip_runtime.h>
#include <math.h>

typedef unsigned short u16;
typedef float f32x4 __attribute__((ext_vector_type(4)));
typedef short s16x4 __attribute__((ext_vector_type(4)));
typedef short s16x8 __attribute__((ext_vector_type(8)));

#define AS3 __attribute__((address_space(3)))
#define AS1 __attribute__((address_space(1)))

__device__ __forceinline__ u16 f2bf(float f) {
  unsigned x = __builtin_bit_cast(unsigned, f);
  x += 0x7fffu + ((x >> 16) & 1u);
  return (u16)(x >> 16);
}
__device__ __forceinline__ float bf2f(u16 u) {
  unsigned x = ((unsigned)u) << 16;
  return __builtin_bit_cast(float, x);
}
__device__ __forceinline__ void gload16(const void* g, void* l) {
  __builtin_amdgcn_global_load_lds((const AS1 void*)g, (AS3 void*)l, 16, 0, 0);
}
// fast sigmoid/tanh via v_exp_f32 (2^x) + v_rcp_f32; ~1ulp, far below bf16 rounding
__device__ __forceinline__ float fsig(float x) {
  return __builtin_amdgcn_rcpf(1.0f + __builtin_amdgcn_exp2f(-1.44269504f * x));
}
__device__ __forceinline__ float ftanh(float x) {
  return 1.0f - 2.0f * __builtin_amdgcn_rcpf(1.0f + __builtin_amdgcn_exp2f(2.88539008f * x));
}

// ---------------- adjacency preprocessing ----------------
__global__ void k_dinv(const float* __restrict__ adj, float* __restrict__ dinv) {
  int j = blockIdx.x;
  float s = 0.0f;
  for (int i = threadIdx.x; i < 512; i += 64) s += adj[(size_t)j * 512 + i];
  #pragma unroll
  for (int off = 32; off > 0; off >>= 1) s += __shfl_down(s, off);
  if (threadIdx.x == 0) dinv[j] = 1.0f / (1.0f + s);
}

// Ab[n][m] = (adj[m][n] + (n==m)) * dinv[m]   (random-walk transpose), bf16
__global__ void k_buildA(const float* __restrict__ adj, const float* __restrict__ dinv,
                         u16* __restrict__ Ab) {
  int i = blockIdx.x;
  for (int j = threadIdx.x; j < 512; j += 256) {
    float v = adj[(size_t)j * 512 + i] + ((i == j) ? 1.0f : 0.0f);
    Ab[(size_t)i * 512 + j] = f2bf(v * dinv[j]);
  }
}

// state fp32 -> node-major bf16 (XG0n) AND f-major bf16 (XG0t), one read
__global__ __launch_bounds__(256) void k_prepST(const float* __restrict__ s,
                                                u16* __restrict__ Xn,
                                                u16* __restrict__ Xt) {
  __shared__ float Tl[64][65];
  const int b = blockIdx.y, n0 = blockIdx.x * 64;
  const int tid = threadIdx.x;
  const int r = tid >> 4, c4 = (tid & 15) * 4;
  #pragma unroll
  for (int i = 0; i < 4; ++i) {
    f32x4 v = *(const f32x4*)&s[((size_t)b * 512 + n0 + i * 16 + r) * 64 + c4];
    s16x4 o;
    #pragma unroll
    for (int j = 0; j < 4; ++j) { Tl[c4 + j][i * 16 + r] = v[j]; o[j] = (short)f2bf(v[j]); }
    *(s16x4*)&Xn[((size_t)b * 512 + n0 + i * 16 + r) * 64 + c4] = o;
  }
  __syncthreads();
  #pragma unroll
  for (int i = 0; i < 4; ++i) {
    int d = i * 16 + r;
    s16x4 o;
    #pragma unroll
    for (int j = 0; j < 4; ++j) o[j] = (short)f2bf(Tl[d][c4 + j]);
    *(s16x4*)&Xt[((size_t)b * 64 + d) * 512 + n0 + c4] = o;
  }
}

// fused weight-permute (gate cols 0..127, cand cols 128..191) + input transpose
// (blocks 192..447). WTp kappa map + Chebyshev folding identical to r13 (proven):
// k1==0 -> W0-W2; k1==1 -> W1; k1==2 -> 2*W2.
__global__ void k_prepW(const float* __restrict__ Wg, const float* __restrict__ Wc,
                        const float* __restrict__ inp,
                        u16* __restrict__ WTpg, u16* __restrict__ WTpc,
                        u16* __restrict__ Xi0t) {
  const int blk = blockIdx.x, tid = threadIdx.x;
  if (blk < 192) {
    if (tid >= 224) return;
    const int NC = (blk < 128) ? 128 : 64;
    const float* W = (blk < 128) ? Wg : Wc;
    u16* WTp = (blk < 128) ? WTpg : WTpc;
    const int col = (blk < 128) ? blk : blk - 128;
    int kt = tid >> 5, g = (tid >> 3) & 3, j = tid & 7;
    int kappa = 32 * kt + 4 * g + ((j < 4) ? j : j + 12);
    float v = 0.0f;
    if (kappa < 192) {
      int f = kappa & 63;
      int k1 = kappa >> 6;
      const float* base = &W[(size_t)((f + 2) * 3) * NC + col];
      v = (k1 == 0) ? base[0] - base[2 * NC]
        : (k1 == 1) ? base[1 * NC]
                    : 2.0f * base[2 * NC];
    } else if (kappa < 198) {
      int t = kappa - 192, k1 = t >> 1, c = t & 1;
      const float* base = &W[(size_t)(c * 3) * NC + col];
      v = (k1 == 0) ? base[0] - base[2 * NC]
        : (k1 == 1) ? base[1 * NC]
                    : 2.0f * base[2 * NC];
    }
    WTp[(size_t)col * 224 + tid] = f2bf(v);
  } else {
    const int b = blk - 192;
    const int m2 = tid * 2;
    f32x4 v = *(const f32x4*)&inp[(size_t)b * 1024 + m2 * 2];
    unsigned p0 = (unsigned)f2bf(v.x) | ((unsigned)f2bf(v.z) << 16);
    unsigned p1 = (unsigned)f2bf(v.y) | ((unsigned)f2bf(v.w) << 16);
    *(unsigned*)&Xi0t[((size_t)b * 2 + 0) * 512 + m2] = p0;
    *(unsigned*)&Xi0t[((size_t)b * 2 + 1) * 512 + m2] = p1;
  }
}

// ---------------- diffusion GEMM: Yt[R][n] = sum_m Xt[R][m]*Ab[n][m] (r11-proven) ----
template<int WTB, int WNB>
__global__ __launch_bounds__(256, 3) void k_diffB(const u16* __restrict__ Xt,
                                                  const u16* __restrict__ Ab,
                                                  u16* __restrict__ Yt,
                                                  u16* __restrict__ Yn) {
  __shared__ __align__(16) u16 SB[16384];
  const int tid = threadIdx.x;
  const int w = tid >> 6, l = tid & 63, g = l >> 4, l16 = l & 15;
  const int Rg = w >> 1, ng = w & 1;
  const int nt0 = blockIdx.x * 128;
  const size_t R0 = (size_t)blockIdx.y * 128;
  const bool isInput = (R0 >= 16384);
  f32x4 acc[4][4] = {};

#define STAGE(BUF, M0)                                                            \
  {                                                                               \
    _Pragma("unroll")                                                             \
    for (int i_ = 0; i_ < 2; ++i_) {                                              \
      int s_ = i_ * 256 + tid, r_ = s_ >> 2, p_ = s_ & 3;                         \
      gload16(&Xt[(R0 + r_) * 512 + (M0) + 8 * (p_ ^ (r_ & 3))],                  \
              &SB[(BUF) * 4096 + s_ * 8]);                                        \
      gload16(&Ab[(size_t)(nt0 + r_) * 512 + (M0) + 8 * (p_ ^ (r_ & 3))],         \
              &SB[8192 + (BUF) * 4096 + s_ * 8]);                                 \
    }                                                                             \
  }

  STAGE(0, 0);
  #pragma unroll
  for (int it = 0; it < 16; ++it) {
    const int cur = it & 1;
    if (it < 15) {
      if (cur == 0) STAGE(1, (it + 1) * 32)
      else          STAGE(0, (it + 1) * 32)
      asm volatile("s_waitcnt vmcnt(4)" ::: "memory");
    } else {
      asm volatile("s_waitcnt vmcnt(0)" ::: "memory");
    }
    __builtin_amdgcn_s_barrier();
    __builtin_amdgcn_sched_barrier(0);

    const u16* XL = &SB[cur * 4096];
    const u16* AL = &SB[8192 + cur * 4096];
    s16x8 af[4], bf[4];
    #pragma unroll
    for (int mt = 0; mt < 4; ++mt) {
      int r = Rg * 64 + mt * 16 + l16;
      const char* rowp = (const char*)XL + r * 64 + 8 * (g & 1);
      int c0 = (g >> 1), c1 = c0 + 2;
      s16x4 lo = *(const s16x4*)(rowp + 16 * (c0 ^ (r & 3)));
      s16x4 hi = *(const s16x4*)(rowp + 16 * (c1 ^ (r & 3)));
      af[mt] = __builtin_shufflevector(lo, hi, 0, 1, 2, 3, 4, 5, 6, 7);
    }
    #pragma unroll
    for (int nt = 0; nt < 4; ++nt) {
      int r = ng * 64 + nt * 16 + l16;
      const char* rowp = (const char*)AL + r * 64 + 8 * (g & 1);
      int c0 = (g >> 1), c1 = c0 + 2;
      s16x4 lo = *(const s16x4*)(rowp + 16 * (c0 ^ (r & 3)));
      s16x4 hi = *(const s16x4*)(rowp + 16 * (c1 ^ (r & 3)));
      bf[nt] = __builtin_shufflevector(lo, hi, 0, 1, 2, 3, 4, 5, 6, 7);
    }
    #pragma unroll
    for (int mt = 0; mt < 4; ++mt)
      #pragma unroll
      for (int nt = 0; nt < 4; ++nt)
        acc[mt][nt] = __builtin_amdgcn_mfma_f32_16x16x32_bf16(af[mt], bf[nt],
                                                              acc[mt][nt], 0, 0, 0);
    __builtin_amdgcn_s_barrier();
    __builtin_amdgcn_sched_barrier(0);
  }
#undef STAGE

  if (WNB && !isInput) {
    #pragma unroll
    for (int mt = 0; mt < 4; ++mt)
      #pragma unroll
      for (int nt = 0; nt < 4; ++nt) {
        size_t R = R0 + Rg * 64 + mt * 16 + 4 * g;
        int n = nt0 + ng * 64 + nt * 16 + l16;
        s16x4 o;
        #pragma unroll
        for (int rr = 0; rr < 4; ++rr) o[rr] = (short)f2bf(acc[mt][nt][rr]);
        *(s16x4*)&Yn[((R >> 6) * 512 + n) * 64 + (R & 63)] = o;
      }
  }

  if (WTB || isInput) {
    #pragma unroll
    for (int mt = 0; mt < 4; ++mt)
      #pragma unroll
      for (int nt = 0; nt < 4; ++nt) {
        int nl = ng * 64 + nt * 16 + l16;
        #pragma unroll
        for (int rr = 0; rr < 4; ++rr) {
          int Rl = Rg * 64 + mt * 16 + 4 * g + rr;
          SB[Rl * 128 + nl] = f2bf(acc[mt][nt][rr]);
        }
      }
    __syncthreads();
    #pragma unroll
    for (int i = 0; i < 8; ++i) {
      int s = i * 256 + tid, r = s >> 4, c = s & 15;
      *(s16x8*)&Yt[(R0 + r) * 512 + nt0 + c * 8] = *(const s16x8*)&SB[r * 128 + c * 8];
    }
  }
}

// ---------------- gate applyW, 32-node tiles: NC=128 (r13-proven) ----------------
__global__ __launch_bounds__(256) void k_applyG(
    const u16* __restrict__ S0b, const u16* __restrict__ S1b, const u16* __restrict__ S2b,
    const float* __restrict__ inp, const u16* __restrict__ Yi1, const u16* __restrict__ Yi2,
    const u16* __restrict__ WTp, const float* __restrict__ bias,
    u16* __restrict__ XC0n, u16* __restrict__ XC0t, u16* __restrict__ Ub) {
  __shared__ __align__(16) u16 Sl[3][2048];   // [32 rows][64 f], swizzled chunks
  __shared__ __align__(16) u16 St[32 * 36];   // tail k-tile [32 rows][36]
  const int tid = threadIdx.x;
  const int w = tid >> 6, l = tid & 63, g = l >> 4, l16 = l & 15;
  const int b = blockIdx.y, n0 = blockIdx.x * 32;
  const int colr = w * 16 + l16;

  const u16* Sb[3] = {S0b, S1b, S2b};
  #pragma unroll
  for (int k1 = 0; k1 < 3; ++k1) {
    int r = tid >> 3, p = tid & 7;
    gload16(&Sb[k1][((size_t)b * 512 + n0 + r) * 64 + 8 * (p ^ (r & 7))],
            &Sl[k1][(w * 64) * 8]);
  }
  s16x8 aw[7][2];
  {
    const u16* w0 = WTp + (size_t)colr * 224 + g * 8;
    const u16* w1 = WTp + (size_t)(colr + 64) * 224 + g * 8;
    #pragma unroll
    for (int kt = 0; kt < 7; ++kt) {
      aw[kt][0] = *(const s16x8*)&w0[kt * 32];
      aw[kt][1] = *(const s16x8*)&w1[kt * 32];
    }
  }
  for (int i = tid; i < 32 * 36; i += 256)
    if ((i % 36) >= 6) St[i] = 0;
  if (tid < 192) {
    int k1 = tid >> 6, rr = (tid >> 1) & 31, c = tid & 1;
    u16 v;
    if (k1 == 0) v = f2bf(inp[((size_t)b * 512 + n0 + rr) * 2 + c]);
    else {
      const u16* Yk = (k1 == 1) ? Yi1 : Yi2;
      v = Yk[((size_t)b * 2 + c) * 512 + (n0 + rr)];
    }
    St[rr * 36 + k1 * 2 + c] = v;
  }
  asm volatile("s_waitcnt vmcnt(0)" ::: "memory");
  __syncthreads();

  f32x4 acc0[2] = {}, acc1[2] = {};
  #pragma unroll
  for (int kt = 0; kt < 7; ++kt) {
    #pragma unroll
    for (int ns = 0; ns < 2; ++ns) {
      int rn = ns * 16 + l16;
      s16x4 lo, hi;
      if (kt < 6) {
        const int buf = kt >> 1, ft = kt & 1;
        int c0 = ft * 4 + (g >> 1), c1 = c0 + 2;
        const char* rowp = (const char*)Sl[buf] + rn * 128 + 8 * (g & 1);
        lo = *(const s16x4*)(rowp + 16 * (c0 ^ (rn & 7)));
        hi = *(const s16x4*)(rowp + 16 * (c1 ^ (rn & 7)));
      } else {
        const char* rowp = (const char*)St + rn * 72 + 8 * g;
        lo = *(const s16x4*)(rowp);
        hi = *(const s16x4*)(rowp + 32);
      }
      s16x8 bs = __builtin_shufflevector(lo, hi, 0, 1, 2, 3, 4, 5, 6, 7);
      acc0[ns] = __builtin_amdgcn_mfma_f32_16x16x32_bf16(aw[kt][0], bs, acc0[ns], 0, 0, 0);
      acc1[ns] = __builtin_amdgcn_mfma_f32_16x16x32_bf16(aw[kt][1], bs, acc1[ns], 0, 0, 0);
    }
  }
  __syncthreads();   // all waves done reading Sl[1] before bounce reuse

  f32x4 b4r = *(const f32x4*)&bias[w * 16 + 4 * g];
  f32x4 b4u = *(const f32x4*)&bias[64 + w * 16 + 4 * g];
  const int chk = 2 * w + (g >> 1);
  #pragma unroll
  for (int ns = 0; ns < 2; ++ns) {
    int rn = ns * 16 + l16;
    int n = n0 + rn;
    size_t base = ((size_t)b * 512 + n) * 64 + w * 16 + 4 * g;
    const char* srow = (const char*)Sl[0] + rn * 128 + 8 * (g & 1);
    s16x4 st4 = *(const s16x4*)(srow + 16 * (chk ^ (rn & 7)));
    s16x4 o;
    #pragma unroll
    for (int r = 0; r < 4; ++r) {
      float x = acc0[ns][r] + b4r[r];
      o[r] = (short)f2bf(fsig(x) * bf2f((u16)st4[r]));
    }
    *(s16x4*)&XC0n[base] = o;
    #pragma unroll
    for (int r = 0; r < 4; ++r)
      Sl[1][(w * 16 + 4 * g + r) * 32 + rn] = (u16)o[r];   // bounce tile [64f][32n]
    s16x4 uo;
    #pragma unroll
    for (int r = 0; r < 4; ++r) {
      float x = acc1[ns][r] + b4u[r];
      uo[r] = (short)f2bf(fsig(x));
    }
    *(s16x4*)&Ub[base] = uo;
  }
  __syncthreads();
  {
    int f = tid >> 2, c = tid & 3;
    *(s16x8*)&XC0t[(size_t)(b * 64 + f) * 512 + n0 + c * 8] =
        *(const s16x8*)&Sl[1][f * 32 + c * 8];
  }
}

// ---------------- candidate applyW, 32-node tiles: NC=64 (r13-proven) ----------
__global__ __launch_bounds__(256) void k_applyC(
    const u16* __restrict__ S0b, const u16* __restrict__ S1b, const u16* __restrict__ S2b,
    const float* __restrict__ inp, const u16* __restrict__ Yi1, const u16* __restrict__ Yi2,
    const u16* __restrict__ WTp, const float* __restrict__ bias,
    const float* __restrict__ state, const u16* __restrict__ Ub, float* __restrict__ outp) {
  __shared__ __align__(16) u16 Sl[3][2048];
  __shared__ __align__(16) u16 St[32 * 36];
  const int tid = threadIdx.x;
  const int w = tid >> 6, l = tid & 63, g = l >> 4, l16 = l & 15;
  const int b = blockIdx.y, n0 = blockIdx.x * 32;
  const int colr = w * 16 + l16;

  const u16* Sb[3] = {S0b, S1b, S2b};
  #pragma unroll
  for (int k1 = 0; k1 < 3; ++k1) {
    int r = tid >> 3, p = tid & 7;
    gload16(&Sb[k1][((size_t)b * 512 + n0 + r) * 64 + 8 * (p ^ (r & 7))],
            &Sl[k1][(w * 64) * 8]);
  }
  s16x8 aw[7];
  {
    const u16* w0 = WTp + (size_t)colr * 224 + g * 8;
    #pragma unroll
    for (int kt = 0; kt < 7; ++kt) aw[kt] = *(const s16x8*)&w0[kt * 32];
  }
  for (int i = tid; i < 32 * 36; i += 256)
    if ((i % 36) >= 6) St[i] = 0;
  if (tid < 192) {
    int k1 = tid >> 6, rr = (tid >> 1) & 31, c = tid & 1;
    u16 v;
    if (k1 == 0) v = f2bf(inp[((size_t)b * 512 + n0 + rr) * 2 + c]);
    else {
      const u16* Yk = (k1 == 1) ? Yi1 : Yi2;
      v = Yk[((size_t)b * 2 + c) * 512 + (n0 + rr)];
    }
    St[rr * 36 + k1 * 2 + c] = v;
  }
  asm volatile("s_waitcnt vmcnt(0)" ::: "memory");
  __syncthreads();

  f32x4 acc[2] = {};
  #pragma unroll
  for (int kt = 0; kt < 7; ++kt) {
    #pragma unroll
    for (int ns = 0; ns < 2; ++ns) {
      int rn = ns * 16 + l16;
      s16x4 lo, hi;
      if (kt < 6) {
        const int buf = kt >> 1, ft = kt & 1;
        int c0 = ft * 4 + (g >> 1), c1 = c0 + 2;
        const char* rowp = (const char*)Sl[buf] + rn * 128 + 8 * (g & 1);
        lo = *(const s16x4*)(rowp + 16 * (c0 ^ (rn & 7)));
        hi = *(const s16x4*)(rowp + 16 * (c1 ^ (rn & 7)));
      } else {
        const char* rowp = (const char*)St + rn * 72 + 8 * g;
        lo = *(const s16x4*)(rowp);
        hi = *(const s16x4*)(rowp + 32);
      }
      s16x8 bs = __builtin_shufflevector(lo, hi, 0, 1, 2, 3, 4, 5, 6, 7);
      acc[ns] = __builtin_amdgcn_mfma_f32_16x16x32_bf16(aw[kt], bs, acc[ns], 0, 0, 0);
    }
  }

  f32x4 b4 = *(const f32x4*)&bias[w * 16 + 4 * g];
  #pragma unroll
  for (int ns = 0; ns < 2; ++ns) {
    int n = n0 + ns * 16 + l16;
    size_t base = ((size_t)b * 512 + n) * 64 + w * 16 + 4 * g;
    s16x4 ub4 = *(const s16x4*)&Ub[base];
    f32x4 st4 = *(const f32x4*)&state[base];
    f32x4 o;
    #pragma unroll
    for (int r = 0; r < 4; ++r) {
      float c = ftanh(acc[ns][r] + b4[r]);
      float u = bf2f((u16)ub4[r]);
      o[r] = fmaf(u, st4[r] - c, c);
    }
    *(f32x4*)&outp[base] = o;
  }
}

extern "C" void kernel_launch(void* const* d_in, const int* in_sizes, int n_in,
                              void* d_out, int out_size, void* d_ws, size_t ws_size,
                              hipStream_t stream) {
  const float* inp   = (const float*)d_in[0];
  const float* state = (const float*)d_in[1];
  const float* adj   = (const float*)d_in[2];
  const float* Wg    = (const float*)d_in[3];
  const float* bg    = (const float*)d_in[4];
  const float* Wc    = (const float*)d_in[5];
  const float* bc    = (const float*)d_in[6];
  float* out = (float*)d_out;

  char* p = (char*)d_ws;
  u16* Abf    = (u16*)p; p += 524288;      // Ab[n][m]
  u16* XAll0t = (u16*)p; p += 17301504;    // [16896][512]: XG0t (later XC0t) + Xi0t tail
  u16* X1t    = (u16*)p; p += 17301504;    // [16896][512]: X1t batch + Yi1t tail
  u16* Yi2t   = (u16*)p; p += 524288;      // [512][512] (plain A@Yi1; weights folded)
  u16* WTpg   = (u16*)p; p += 57344;       // [128][224] permuted + folded
  u16* WTpc   = (u16*)p; p += 28672;       // [64][224]
  float* dinv = (float*)p; p += 2048;
  u16* XG0n   = (u16*)p; p += 16777216;    // [b][n][64]; reused as Ub after applyG stages it
  u16* XC0n   = (u16*)p; p += 16777216;
  u16* X1n    = (u16*)p; p += 16777216;
  u16* X2n    = (u16*)p; p += 16777216;    // total ~98.1 MB
  u16* Xi0t   = XAll0t + (size_t)16384 * 512;
  u16* XC0t   = XAll0t;                    // alias: XG0t dead after gate hop1
  u16* Yi1t   = X1t + (size_t)16384 * 512;
  u16* Yi2off = Yi2t - (size_t)16384 * 512;  // Yt base for hop2 (only R>=16384 deref'd)
  u16* Ub     = XG0n;                      // alias: same-block footprint, staged before written

  k_dinv   <<<512, 64,  0, stream>>>(adj, dinv);
  k_buildA <<<512, 256, 0, stream>>>(adj, dinv, Abf);
  k_prepST <<<dim3(8, 256), 256, 0, stream>>>(state, XG0n, XAll0t);
  k_prepW  <<<448, 256, 0, stream>>>(Wg, Wc, inp, WTpg, WTpc, Xi0t);

  // gate hop1 (batch + input rows) -> X1t (+Yi1t tail), X1n
  k_diffB<1, 1><<<dim3(4, 132), 256, 0, stream>>>(XAll0t, Abf, X1t, X1n);
  // gate hop2 (plain A@X1, folded): batch -> X2n; input rows -> Yi2t
  k_diffB<0, 1><<<dim3(4, 132), 256, 0, stream>>>(X1t, Abf, Yi2off, X2n);
  k_applyG<<<dim3(16, 256), 256, 0, stream>>>(XG0n, X1n, X2n, inp, Yi1t, Yi2t,
                                              WTpg, bg, XC0n, XC0t, Ub);

  // candidate path (batch rows only; input diffusion reused)
  k_diffB<1, 1><<<dim3(4, 128), 256, 0, stream>>>(XC0t, Abf, X1t, X1n);
  k_diffB<0, 1><<<dim3(4, 128), 256, 0, stream>>>(X1t, Abf, Yi2off, X2n);
  k_applyC<<<dim3(16, 256), 256, 0, stream>>>(XC0n, X1n, X2n, inp, Yi1t, Yi2t,
                                              WTpc, bc, state, Ub, out);
}